// Round 11
// baseline (189.398 us; speedup 1.0000x reference)
//
#include <hip/hip_runtime.h>

// Problem constants (fixed by reference setup_inputs)
#define NB 65536   // batch
#define NT 64      // time points -> 63 Euler steps
#define NH 64      // hidden width (ode + classifier)
#define NC 3       // classes

typedef float v2 __attribute__((ext_vector_type(2)));

#define TANH_K 2.885390081777927f  // 2*log2(e): tanh(x) = 1 - 2/(exp2(K*x)+1)

// ---- DPP helpers (quad_perm, pure VALU, no LDS) ----
template <int CTRL>
__device__ __forceinline__ float dpp_mov(float x) {
#if __has_builtin(__builtin_amdgcn_update_dpp)
    return __int_as_float(__builtin_amdgcn_update_dpp(
        0, __float_as_int(x), CTRL, 0xF, 0xF, true));
#else
    // CTRL 0xB1 = xor1, 0x4E = xor2
    return __shfl_xor(x, (CTRL == 0xB1) ? 1 : 2, 64);
#endif
}

__device__ __forceinline__ float quad_sum(float x) {
    x += dpp_mov<0xB1>(x);  // xor 1
    x += dpp_mov<0x4E>(x);  // xor 2
    return x;
}

// ================= fused ODE + classifier, 4 lanes per element =================
// Lane sub = gid&3 owns hidden units j in [16*sub, 16*sub+16).
__global__ __launch_bounds__(256, 4) void node_all(
    const float* __restrict__ y0, const float* __restrict__ t,
    const float* __restrict__ W1,  const float* __restrict__ b1,
    const float* __restrict__ W2,  const float* __restrict__ b2,
    const float* __restrict__ Wc1, const float* __restrict__ bc1,
    const float* __restrict__ Wc2, const float* __restrict__ bc2,
    const float* __restrict__ Wc3, const float* __restrict__ bc3,
    float* __restrict__ out)
{
    const int gid  = blockIdx.x * blockDim.x + threadIdx.x;
    const int elem = gid >> 2;
    const int sub  = gid & 3;
    const int jb   = sub << 4;            // 16*sub

    // ---- one-time weight preload (per-lane 16-unit slice), algebraically folded ----
    // pre' = K*(yA*W1[0][j] + yB*W1[1][j] + b1[j]);  tanh = 1 - 2*rcp(exp2(pre')+1)
    // f_c  = sum_j tanh_j*W2[j][c] = (sum_j W2[j][c]) + sum_j r_j*(-2*W2[j][c])
    v2 w1k[8], w1k2[8], b1k[8], w2na[8], w2nb[8];
    float sa = 0.0f, sb = 0.0f;
    #pragma unroll
    for (int p = 0; p < 8; ++p) {
        const int j = jb + 2 * p;
        w1k [p] = *reinterpret_cast<const v2*>(W1 + j)      * TANH_K;
        w1k2[p] = *reinterpret_cast<const v2*>(W1 + NH + j) * TANH_K;
        b1k [p] = *reinterpret_cast<const v2*>(b1 + j)      * TANH_K;
        v2 q0 = *reinterpret_cast<const v2*>(W2 + 2 * j);       // {W2[j][0],   W2[j][1]}
        v2 q1 = *reinterpret_cast<const v2*>(W2 + 2 * j + 2);   // {W2[j+1][0], W2[j+1][1]}
        v2 na = {-2.0f * q0.x, -2.0f * q1.x}; w2na[p] = na;     // -2 * column 0
        v2 nb = {-2.0f * q0.y, -2.0f * q1.y}; w2nb[p] = nb;     // -2 * column 1
        sa += q0.x + q1.x;
        sb += q0.y + q1.y;
    }
    // Pin weights into VGPRs: opaque asm makes rematerialization of the loads
    // impossible, so the 63-step loop is pure VALU/trans (round-6 showed LLVM
    // re-loading weights in-loop: VGPR_Count=88 for 160 live floats).
    #pragma unroll
    for (int p = 0; p < 8; ++p) {
        asm volatile("" : "+v"(w1k[p]), "+v"(w1k2[p]), "+v"(b1k[p]),
                          "+v"(w2na[p]), "+v"(w2nb[p]));
    }

    v2 yv = *reinterpret_cast<const v2*>(y0 + 2 * elem);
    float yA = yv.x, yB = yv.y;
    const float b20 = b2[0], b21 = b2[1];

    // ---- 63 Euler steps ----
    for (int s = 0; s < NT - 1; ++s) {
        const float dt = t[s + 1] - t[s];
        const v2 yAv = {yA, yA}, yBv = {yB, yB};
        v2 f0 = {0.0f, 0.0f}, f1 = {0.0f, 0.0f};
        #pragma unroll
        for (int p = 0; p < 8; ++p) {
            v2 pre = __builtin_elementwise_fma(yAv, w1k[p],
                     __builtin_elementwise_fma(yBv, w1k2[p], b1k[p]));
            v2 e = {__builtin_amdgcn_exp2f(pre.x), __builtin_amdgcn_exp2f(pre.y)};
            v2 d = e + 1.0f;
            v2 r = {__builtin_amdgcn_rcpf(d.x), __builtin_amdgcn_rcpf(d.y)};
            f0 = __builtin_elementwise_fma(r, w2na[p], f0);
            f1 = __builtin_elementwise_fma(r, w2nb[p], f1);
        }
        float F0 = quad_sum(sa + f0.x + f0.y) + b20;
        float F1 = quad_sum(sb + f1.x + f1.y) + b21;
        yA = fmaf(dt, F0, yA);
        yB = fmaf(dt, F1, yB);
    }

    // ---- fused classifier (per-lane 16-wide slice of each layer) ----
    // h1: my 16 units
    float h1o[16];
    #pragma unroll
    for (int i = 0; i < 16; ++i) {
        const int j = jb + i;
        h1o[i] = fmaxf(fmaf(yA, Wc1[j], fmaf(yB, Wc1[NH + j], bc1[j])), 0.0f);
    }

    // h2[j' in my 16 cols] = bc2 + sum_k h1[k] * Wc2[k][j'] ; k gathered across quad
    v2 acc[8];
    #pragma unroll
    for (int p = 0; p < 8; ++p)
        acc[p] = *reinterpret_cast<const v2*>(bc2 + jb + 2 * p);

    const int kb0 = jb;                // rows owned by me
    const int kb1 = (sub ^ 1) << 4;    // rows from lane xor1
    const int kb2 = (sub ^ 2) << 4;    // rows from lane xor2
    const int kb3 = (sub ^ 3) << 4;    // rows from lane xor3

    #define PROC_GROUP(arr, kb)                                                   \
        _Pragma("unroll")                                                         \
        for (int i = 0; i < 16; ++i) {                                            \
            const float hk = arr[i];                                              \
            const v2 hv = {hk, hk};                                               \
            const float* row = Wc2 + ((kb) + i) * NH + jb;                        \
            _Pragma("unroll")                                                     \
            for (int p = 0; p < 8; ++p)                                           \
                acc[p] = __builtin_elementwise_fma(                               \
                    hv, *reinterpret_cast<const v2*>(row + 2 * p), acc[p]);       \
        }

    PROC_GROUP(h1o, kb0)
    float h1b[16];
    #pragma unroll
    for (int i = 0; i < 16; ++i) h1b[i] = dpp_mov<0xB1>(h1o[i]);
    PROC_GROUP(h1b, kb1)
    float h1c[16];
    #pragma unroll
    for (int i = 0; i < 16; ++i) h1c[i] = dpp_mov<0x4E>(h1o[i]);
    PROC_GROUP(h1c, kb2)
    float h1d[16];
    #pragma unroll
    for (int i = 0; i < 16; ++i) h1d[i] = dpp_mov<0x4E>(h1b[i]);
    PROC_GROUP(h1d, kb3)
    #undef PROC_GROUP

    // out = relu(h2) @ Wc3 + bc3 ; partial over my 16 j's, then quad reduce
    float o0 = 0.0f, o1 = 0.0f, o2 = 0.0f;
    #pragma unroll
    for (int p = 0; p < 8; ++p) {
        const float hx = fmaxf(acc[p].x, 0.0f);
        const float hy = fmaxf(acc[p].y, 0.0f);
        const int j0 = jb + 2 * p;
        o0 = fmaf(hx, Wc3[3 * j0 + 0], o0);
        o1 = fmaf(hx, Wc3[3 * j0 + 1], o1);
        o2 = fmaf(hx, Wc3[3 * j0 + 2], o2);
        o0 = fmaf(hy, Wc3[3 * j0 + 3], o0);
        o1 = fmaf(hy, Wc3[3 * j0 + 4], o1);
        o2 = fmaf(hy, Wc3[3 * j0 + 5], o2);
    }
    o0 = quad_sum(o0) + bc3[0];
    o1 = quad_sum(o1) + bc3[1];
    o2 = quad_sum(o2) + bc3[2];

    // lanes 0..2 of each quad write one component each (contiguous coverage)
    if (sub < 3) {
        const float o = (sub == 0) ? o0 : (sub == 1) ? o1 : o2;
        out[3 * elem + sub] = o;
    }
}

extern "C" void kernel_launch(void* const* d_in, const int* in_sizes, int n_in,
                              void* d_out, int out_size, void* d_ws, size_t ws_size,
                              hipStream_t stream) {
    (void)in_sizes; (void)n_in; (void)out_size; (void)d_ws; (void)ws_size;
    const float* y0  = (const float*)d_in[0];
    const float* t   = (const float*)d_in[1];
    const float* W1  = (const float*)d_in[2];
    const float* b1  = (const float*)d_in[3];
    const float* W2  = (const float*)d_in[4];
    const float* b2  = (const float*)d_in[5];
    const float* Wc1 = (const float*)d_in[6];
    const float* bc1 = (const float*)d_in[7];
    const float* Wc2 = (const float*)d_in[8];
    const float* bc2 = (const float*)d_in[9];
    const float* Wc3 = (const float*)d_in[10];
    const float* bc3 = (const float*)d_in[11];
    float* out = (float*)d_out;

    // 4 lanes per element -> 262144 threads = 4096 waves = 4 waves/SIMD
    hipLaunchKernelGGL(node_all, dim3(NB * 4 / 256), dim3(256), 0, stream,
                       y0, t, W1, b1, W2, b2, Wc1, bc1, Wc2, bc2, Wc3, bc3, out);
}

// Round 16
// 148.456 us; speedup vs baseline: 1.2758x; 1.2758x over previous
//
#include <hip/hip_runtime.h>

// Problem constants (fixed by reference setup_inputs)
#define NB 65536   // batch
#define NT 64      // time points -> 63 Euler steps
#define NH 64      // hidden width (ode + classifier)
#define NC 3       // classes

typedef float v2 __attribute__((ext_vector_type(2)));

#define TANH_K 2.885390081777927f  // 2*log2(e): tanh(x) = 1 - 2/(exp2(K*x)+1)

// ---- cross-lane helpers (no LDS memory, permute networks only) ----
template <int CTRL>
__device__ __forceinline__ float dpp_mov(float x) {
    return __int_as_float(__builtin_amdgcn_update_dpp(
        0, __float_as_int(x), CTRL, 0xF, 0xF, true));
}
// xor1 = quad_perm[1,0,3,2] = 0xB1 ; xor2 = quad_perm[2,3,0,1] = 0x4E

__device__ __forceinline__ float swz4(float x) {   // lane ^= 4 (BitMode 0x101F)
    return __int_as_float(__builtin_amdgcn_ds_swizzle(__float_as_int(x), 0x101F));
}

__device__ __forceinline__ float oct_sum(float x) {
    x += dpp_mov<0xB1>(x);   // xor 1
    x += dpp_mov<0x4E>(x);   // xor 2
    x += swz4(x);            // xor 4
    return x;
}

// ============ fused ODE + classifier, 8 lanes per element ============
// Lane sub = gid&7 owns hidden units j in [8*sub, 8*sub+8).
// Weights: 40 floats/lane -> natural VGPR residency (round-11 post-mortem:
// 80 floats + asm pin => scratch spill, WRITE_SIZE 15 MB. No pin here.)
__global__ __launch_bounds__(256, 4) void node_all8(
    const float* __restrict__ y0, const float* __restrict__ t,
    const float* __restrict__ W1,  const float* __restrict__ b1,
    const float* __restrict__ W2,  const float* __restrict__ b2,
    const float* __restrict__ Wc1, const float* __restrict__ bc1,
    const float* __restrict__ Wc2, const float* __restrict__ bc2,
    const float* __restrict__ Wc3, const float* __restrict__ bc3,
    float* __restrict__ out)
{
    const int gid  = blockIdx.x * blockDim.x + threadIdx.x;
    const int elem = gid >> 3;
    const int sub  = gid & 7;
    const int jb   = sub << 3;            // 8*sub

    // ---- folded weight preload (per-lane 8-unit slice) ----
    // pre' = K*(yA*W1[0][j] + yB*W1[1][j] + b1[j]);  tanh = 1 - 2*rcp(exp2(pre')+1)
    // f_c  = (sum_j W2[j][c]) + sum_j r_j*(-2*W2[j][c])
    v2 w1k[4], w1k2[4], b1k[4], w2na[4], w2nb[4];
    float sa = 0.0f, sb = 0.0f;
    #pragma unroll
    for (int p = 0; p < 4; ++p) {
        const int j = jb + 2 * p;
        w1k [p] = *reinterpret_cast<const v2*>(W1 + j)      * TANH_K;
        w1k2[p] = *reinterpret_cast<const v2*>(W1 + NH + j) * TANH_K;
        b1k [p] = *reinterpret_cast<const v2*>(b1 + j)      * TANH_K;
        v2 q0 = *reinterpret_cast<const v2*>(W2 + 2 * j);       // {W2[j][0],   W2[j][1]}
        v2 q1 = *reinterpret_cast<const v2*>(W2 + 2 * j + 2);   // {W2[j+1][0], W2[j+1][1]}
        v2 na = {-2.0f * q0.x, -2.0f * q1.x}; w2na[p] = na;     // -2 * column 0
        v2 nb = {-2.0f * q0.y, -2.0f * q1.y}; w2nb[p] = nb;     // -2 * column 1
        sa += q0.x + q1.x;
        sb += q0.y + q1.y;
    }

    v2 yv = *reinterpret_cast<const v2*>(y0 + 2 * elem);
    float yA = yv.x, yB = yv.y;
    const float b20 = b2[0], b21 = b2[1];

    // ---- 63 Euler steps ----
    for (int s = 0; s < NT - 1; ++s) {
        const float dt = t[s + 1] - t[s];
        const v2 yAv = {yA, yA}, yBv = {yB, yB};
        v2 f0 = {0.0f, 0.0f}, f1 = {0.0f, 0.0f};
        #pragma unroll
        for (int p = 0; p < 4; ++p) {
            v2 pre = __builtin_elementwise_fma(yAv, w1k[p],
                     __builtin_elementwise_fma(yBv, w1k2[p], b1k[p]));
            v2 e = {__builtin_amdgcn_exp2f(pre.x), __builtin_amdgcn_exp2f(pre.y)};
            v2 d = e + 1.0f;
            v2 r = {__builtin_amdgcn_rcpf(d.x), __builtin_amdgcn_rcpf(d.y)};
            f0 = __builtin_elementwise_fma(r, w2na[p], f0);
            f1 = __builtin_elementwise_fma(r, w2nb[p], f1);
        }
        const float F0 = oct_sum(sa + f0.x + f0.y) + b20;
        const float F1 = oct_sum(sb + f1.x + f1.y) + b21;
        yA = fmaf(dt, F0, yA);
        yB = fmaf(dt, F1, yB);
    }

    // ---- fused classifier (8 h1-units and 8 h2-cols per lane) ----
    float h1o[8];
    #pragma unroll
    for (int i = 0; i < 8; ++i) {
        const int j = jb + i;
        h1o[i] = fmaxf(fmaf(yA, Wc1[j], fmaf(yB, Wc1[NH + j], bc1[j])), 0.0f);
    }

    v2 acc[4];
    #pragma unroll
    for (int p = 0; p < 4; ++p)
        acc[p] = *reinterpret_cast<const v2*>(bc2 + jb + 2 * p);

    // h2[cols jb..jb+8) = bc2 + sum_k h1[k]*Wc2[k][col]; k gathered across oct
    #define PROC_GROUP(arr, krow)                                                 \
        _Pragma("unroll")                                                         \
        for (int i = 0; i < 8; ++i) {                                             \
            const float hk = arr[i];                                              \
            const v2 hv = {hk, hk};                                               \
            const float* row = Wc2 + ((krow) + i) * NH + jb;                      \
            _Pragma("unroll")                                                     \
            for (int p = 0; p < 4; ++p)                                           \
                acc[p] = __builtin_elementwise_fma(                               \
                    hv, *reinterpret_cast<const v2*>(row + 2 * p), acc[p]);       \
        }

    // d = 0..3 via DPP quad_perm gathers, then d = 4..7 via lane^4 swizzle
    float hx1[8], hx2[8], hx3[8];
    #pragma unroll
    for (int i = 0; i < 8; ++i) hx1[i] = dpp_mov<0xB1>(h1o[i]);  // lane^1
    #pragma unroll
    for (int i = 0; i < 8; ++i) hx2[i] = dpp_mov<0x4E>(h1o[i]);  // lane^2
    #pragma unroll
    for (int i = 0; i < 8; ++i) hx3[i] = dpp_mov<0x4E>(hx1[i]);  // lane^3

    PROC_GROUP(h1o, ((sub ^ 0) << 3))
    PROC_GROUP(hx1, ((sub ^ 1) << 3))
    PROC_GROUP(hx2, ((sub ^ 2) << 3))
    PROC_GROUP(hx3, ((sub ^ 3) << 3))

    #pragma unroll
    for (int i = 0; i < 8; ++i) h1o[i] = swz4(h1o[i]);           // lane^4
    #pragma unroll
    for (int i = 0; i < 8; ++i) hx1[i] = swz4(hx1[i]);           // lane^5
    #pragma unroll
    for (int i = 0; i < 8; ++i) hx2[i] = swz4(hx2[i]);           // lane^6
    #pragma unroll
    for (int i = 0; i < 8; ++i) hx3[i] = swz4(hx3[i]);           // lane^7

    PROC_GROUP(h1o, ((sub ^ 4) << 3))
    PROC_GROUP(hx1, ((sub ^ 5) << 3))
    PROC_GROUP(hx2, ((sub ^ 6) << 3))
    PROC_GROUP(hx3, ((sub ^ 7) << 3))
    #undef PROC_GROUP

    // out = relu(h2) @ Wc3 + bc3 ; partial over my 8 cols, then oct reduce
    float o0 = 0.0f, o1 = 0.0f, o2 = 0.0f;
    #pragma unroll
    for (int p = 0; p < 4; ++p) {
        const float hx = fmaxf(acc[p].x, 0.0f);
        const float hy = fmaxf(acc[p].y, 0.0f);
        const int j0 = jb + 2 * p;
        o0 = fmaf(hx, Wc3[3 * j0 + 0], o0);
        o1 = fmaf(hx, Wc3[3 * j0 + 1], o1);
        o2 = fmaf(hx, Wc3[3 * j0 + 2], o2);
        o0 = fmaf(hy, Wc3[3 * j0 + 3], o0);
        o1 = fmaf(hy, Wc3[3 * j0 + 4], o1);
        o2 = fmaf(hy, Wc3[3 * j0 + 5], o2);
    }
    o0 = oct_sum(o0) + bc3[0];
    o1 = oct_sum(o1) + bc3[1];
    o2 = oct_sum(o2) + bc3[2];

    // lanes 0..2 of each oct write one component each
    if (sub < 3) {
        const float o = (sub == 0) ? o0 : (sub == 1) ? o1 : o2;
        out[3 * elem + sub] = o;
    }
}

extern "C" void kernel_launch(void* const* d_in, const int* in_sizes, int n_in,
                              void* d_out, int out_size, void* d_ws, size_t ws_size,
                              hipStream_t stream) {
    (void)in_sizes; (void)n_in; (void)out_size; (void)d_ws; (void)ws_size;
    const float* y0  = (const float*)d_in[0];
    const float* t   = (const float*)d_in[1];
    const float* W1  = (const float*)d_in[2];
    const float* b1  = (const float*)d_in[3];
    const float* W2  = (const float*)d_in[4];
    const float* b2  = (const float*)d_in[5];
    const float* Wc1 = (const float*)d_in[6];
    const float* bc1 = (const float*)d_in[7];
    const float* Wc2 = (const float*)d_in[8];
    const float* bc2 = (const float*)d_in[9];
    const float* Wc3 = (const float*)d_in[10];
    const float* bc3 = (const float*)d_in[11];
    float* out = (float*)d_out;

    // 8 lanes per element -> 524288 threads = 8192 waves (~6-8 waves/SIMD)
    hipLaunchKernelGGL(node_all8, dim3(NB * 8 / 256), dim3(256), 0, stream,
                       y0, t, W1, b1, W2, b2, Wc1, bc1, Wc2, bc2, Wc3, bc3, out);
}